// Round 3
// baseline (2690.268 us; speedup 1.0000x reference)
//
#include <hip/hip_runtime.h>
#include <hip/hip_bf16.h>
#include <math.h>

#define BB 16
#define TT 1024
#define SS 1024
#define CCH 512
#define EE 768
#define EPSV 1e-15f
#define CLIPV (1.0f - 1e-5f)

__device__ __forceinline__ float block_sum(float v, float* red) {
  int t = threadIdx.x;
  red[t] = v; __syncthreads();
  #pragma unroll
  for (int s = 128; s > 0; s >>= 1) { if (t < s) red[t] += red[t + s]; __syncthreads(); }
  float r = red[0]; __syncthreads();
  return r;
}

__device__ __forceinline__ float block_max(float v, float* red) {
  int t = threadIdx.x;
  red[t] = v; __syncthreads();
  #pragma unroll
  for (int s = 128; s > 0; s >>= 1) { if (t < s) red[t] = fmaxf(red[t], red[t + s]); __syncthreads(); }
  float r = red[0]; __syncthreads();
  return r;
}

// ---------- mask dtype detection + conversion ----------
// bool8 layout: nonzero bytes at i%4!=0 (masked runs >= 1 elem per row with
// prob ~1). int32 0/1 layout: within first B*S bytes only bytes i%4==0 can be
// nonzero. Canonicalize to float 0/1.
__global__ void k_maskdet(const unsigned char* __restrict__ mb, int* __restrict__ flag) {
  __shared__ int any;
  if (threadIdx.x == 0) any = 0;
  __syncthreads();
  int local = 0;
  for (int i = threadIdx.x; i < BB * SS; i += 256)
    if ((i & 3) && mb[i]) local = 1;
  if (local) atomicOr(&any, 1);
  __syncthreads();
  if (threadIdx.x == 0) *flag = any;
}

__global__ void k_maskconv(const void* __restrict__ mraw, const int* __restrict__ flag,
                           float* __restrict__ fmask) {
  int i = blockIdx.x * 256 + threadIdx.x;
  if (i >= BB * SS) return;
  int f = *flag;
  int v = f ? (int)((const unsigned char*)mraw)[i] : ((const int*)mraw)[i];
  fmask[i] = v ? 1.0f : 0.0f;
}

// ---------- prep ----------

// column norms of z [K,N]: zn[e] = sqrt(max(sum_k z[k,e]^2, EPS))
__global__ void k_colnorm(const float* __restrict__ z, float* __restrict__ zn, int K, int N) {
  int e = blockIdx.x * blockDim.x + threadIdx.x;
  if (e >= N) return;
  float s = 0.f;
  for (int k = 0; k < K; k++) { float v = z[(long)k * N + e]; s += v * v; }
  zn[e] = sqrtf(fmaxf(s, EPSV));
}

// row sum-of-squares (rows of length D)
__global__ void k_row2(const float* __restrict__ xp, float* __restrict__ out, int D) {
  __shared__ float red[256];
  long row = blockIdx.x;
  float s = 0.f;
  for (int c = threadIdx.x; c < D; c += 256) { float v = xp[row * D + c]; s += v * v; }
  s = block_sum(s, red);
  if (threadIdx.x == 0) out[row] = s;
}

// gam[b,s] = 2/max(1-|encb row|^2, EPS); encbs[b,s,:] = gam * encb[b,s,:]
__global__ void k_scaleB(const float* __restrict__ encb, float* __restrict__ encbs,
                         float* __restrict__ gam) {
  __shared__ float red[256];
  long row = blockIdx.x;  // b*S + s
  int t = threadIdx.x;
  float v[3];
  float s2 = 0.f;
  #pragma unroll
  for (int j = 0; j < 3; j++) { v[j] = encb[row * EE + t + j * 256]; s2 += v[j] * v[j]; }
  s2 = block_sum(s2, red);
  float g = 2.0f / fmaxf(1.0f - s2, EPSV);
  #pragma unroll
  for (int j = 0; j < 3; j++) encbs[row * EE + t + j * 256] = g * v[j];
  if (t == 0) gam[row] = g;
}

// y2a[b,s] = sum_e enc_a[b,e,s]^2   (enc_a is [B,E,S])
__global__ void k_y2a(const float* __restrict__ enca, float* __restrict__ y2a) {
  int idx = blockIdx.x * 256 + threadIdx.x;
  if (idx >= BB * SS) return;
  int b = idx / SS, s = idx % SS;
  const float* p = enca + (long)b * EE * SS + s;
  float acc = 0.f;
  for (int e = 0; e < EE; e++) { float v = p[(long)e * SS]; acc += v * v; }
  y2a[idx] = acc;
}

__global__ void k_sb(const float* __restrict__ fmask, float* __restrict__ ssb) {
  __shared__ float red[256];
  int b = blockIdx.x;
  float cnt = 0.f;
  for (int s = threadIdx.x; s < SS; s += 256) cnt += fmask[(long)b * SS + s];
  cnt = block_sum(cnt, red);
  if (threadIdx.x == 0) ssb[b] = sqrtf((float)SS - cnt);
}

// ---------- tiled GEMM  C = A @ B (f32), optional fused distance epilogue ----------
template <int EPI>
__global__ void gemm_k(const float* __restrict__ A, const float* __restrict__ Bm,
                       float* __restrict__ Cm, int M, int N, int K,
                       long sA, long sB, long sC,
                       const float* __restrict__ q2, const float* __restrict__ y2a,
                       const float* __restrict__ fmask, const float* __restrict__ scalep) {
  __shared__ float As[16][65];
  __shared__ float Bs[16][65];
  int z = blockIdx.z;
  const float* Ab = A + (long)z * sA;
  const float* Bb = Bm + (long)z * sB;
  float* Cb = Cm + (long)z * sC;
  int m0 = blockIdx.y * 64, n0 = blockIdx.x * 64;
  int t = threadIdx.x;
  int tx = t & 15, ty = t >> 4;
  float acc[4][4] = {{0.f}};

  for (int k0 = 0; k0 < K; k0 += 16) {
    #pragma unroll
    for (int u = 0; u < 4; u++) {
      int idx = t + u * 256;
      int k = idx & 15, m = idx >> 4;
      As[k][m] = Ab[(long)(m0 + m) * K + k0 + k];
    }
    #pragma unroll
    for (int u = 0; u < 4; u++) {
      int idx = t + u * 256;
      int n = idx & 63, k = idx >> 6;
      Bs[k][n] = Bb[(long)(k0 + k) * N + n0 + n];
    }
    __syncthreads();
    #pragma unroll
    for (int kk = 0; kk < 16; kk++) {
      float ar[4], br[4];
      #pragma unroll
      for (int i = 0; i < 4; i++) ar[i] = As[kk][ty * 4 + i];
      #pragma unroll
      for (int j = 0; j < 4; j++) br[j] = Bs[kk][tx * 4 + j];
      #pragma unroll
      for (int i = 0; i < 4; i++)
        #pragma unroll
        for (int j = 0; j < 4; j++) acc[i][j] = fmaf(ar[i], br[j], acc[i][j]);
    }
    __syncthreads();
  }

  float inv_es = 1.0f;
  if constexpr (EPI == 1) { inv_es = 1.0f / expf(scalep[0]); }

  #pragma unroll
  for (int i = 0; i < 4; i++) {
    int gm = m0 + ty * 4 + i;
    #pragma unroll
    for (int j = 0; j < 4; j++) {
      int gn = n0 + tx * 4 + j;
      float c = acc[i][j];
      if constexpr (EPI == 0) {
        Cb[(long)gm * N + gn] = c;
      } else {
        float xv = q2[(long)z * M + gm];
        float yv = y2a[(long)z * N + gn];
        float num = fmaxf(xv - 2.0f * c + yv, 0.0f);
        float den = fmaxf(1.0f - 2.0f * c + xv * yv, EPSV);
        float mm = sqrtf(num / den);
        float sc = -2.0f * atanhf(fminf(mm, CLIPV)) * inv_es;
        if (fmask[(long)z * N + gn] > 0.5f) sc = -INFINITY;
        Cb[(long)gm * N + gn] = sc;
      }
    }
  }
}

// ---------- q = msm(sqrt(.5), mobius_add(tgt, poincare_linear(x,w_in,b_in))) ----------
__global__ void k_q(float* __restrict__ Q, const float* __restrict__ tgt,
                    const float* __restrict__ bin, const float* __restrict__ znin,
                    const float* __restrict__ x2, float* __restrict__ q2) {
  __shared__ float red[256];
  long row = blockIdx.x;
  int t = threadIdx.x;
  float cx2 = x2[row];
  float dpl = fmaxf(1.0f - cx2, EPSV);

  float wv[3]; float sw2 = 0.f;
  #pragma unroll
  for (int j = 0; j < 3; j++) {
    int e = t + j * 256;
    float zn = znin[e];
    float u = Q[row * EE + e] / zn;
    float r2 = 2.0f * bin[e];
    float nm = 2.0f * u * coshf(r2) - (1.0f + cx2) * sinhf(r2);
    float y = 2.0f * zn * asinhf(nm / dpl);
    wv[j] = sinhf(y);
    sw2 += wv[j] * wv[j];
  }
  sw2 = block_sum(sw2, red);
  float pden = 1.0f + sqrtf(1.0f + sw2);

  float pv[3], tv[3];
  float tp = 0.f, p2 = 0.f, t2 = 0.f;
  #pragma unroll
  for (int j = 0; j < 3; j++) {
    int e = t + j * 256;
    pv[j] = wv[j] / pden;
    tv[j] = tgt[row * EE + e];
    tp += tv[j] * pv[j]; p2 += pv[j] * pv[j]; t2 += tv[j] * tv[j];
  }
  tp = block_sum(tp, red);
  p2 = block_sum(p2, red);
  t2 = block_sum(t2, red);

  float mden = fmaxf(1.0f + 2.0f * tp + t2 * p2, EPSV);
  float cT = 1.0f + 2.0f * tp + p2;
  float cP = 1.0f - t2;
  float av[3]; float n2 = 0.f;
  #pragma unroll
  for (int j = 0; j < 3; j++) { av[j] = (cT * tv[j] + cP * pv[j]) / mden; n2 += av[j] * av[j]; }
  n2 = block_sum(n2, red);

  float n = sqrtf(fmaxf(n2, EPSV));
  float f = tanhf(0.70710678118654752f * atanhf(fminf(n, CLIPV))) / n;
  #pragma unroll
  for (int j = 0; j < 3; j++) { int e = t + j * 256; Q[row * EE + e] = f * av[j]; }
  if (t == 0) q2[row] = f * f * n2;
}

// ---------- softmax in-place on attn region; den = sum attn*(gamma-1) ----------
__global__ void k_softmax(float* __restrict__ A, const float* __restrict__ gam,
                          float* __restrict__ denr) {
  __shared__ float red[256];
  long row = blockIdx.x;  // b*T + t
  int b = (int)(row / TT);
  int t = threadIdx.x;
  float* rowp = A + row * SS;

  float v[4];
  float mx = -INFINITY;
  #pragma unroll
  for (int j = 0; j < 4; j++) { v[j] = rowp[t + j * 256]; mx = fmaxf(mx, v[j]); }
  mx = block_max(mx, red);
  bool dead = !(mx > -INFINITY) || (mx != mx);
  float sum = 0.f;
  #pragma unroll
  for (int j = 0; j < 4; j++) { v[j] = dead ? 0.f : expf(v[j] - mx); sum += v[j]; }
  sum = block_sum(sum, red);
  float inv = (sum > 0.f) ? 1.0f / sum : 0.f;
  float ds = 0.f;
  #pragma unroll
  for (int j = 0; j < 4; j++) {
    int s = t + j * 256;
    float a = v[j] * inv;
    rowp[s] = a;
    ds += a * (gam[(long)b * SS + s] - 1.0f);
  }
  ds = block_sum(ds, red);
  if (t == 0) denr[row] = (inv == 0.f) ? 1.0f : ds;
}

// ---------- out2 = msm(sqrt(s_b), msm(0.5, nom/den)); Q holds nom, overwritten ----------
__global__ void k_mid(float* __restrict__ Q, const float* __restrict__ denr,
                      const float* __restrict__ ssb, float* __restrict__ o2) {
  __shared__ float red[256];
  long row = blockIdx.x;
  int b = (int)(row / TT);
  int t = threadIdx.x;
  float d = denr[row];
  if (fabsf(d) < 1e-10f) d = 1e-10f;

  float v[3]; float n2 = 0.f;
  #pragma unroll
  for (int j = 0; j < 3; j++) { int e = t + j * 256; v[j] = Q[row * EE + e] / d; n2 += v[j] * v[j]; }
  n2 = block_sum(n2, red);
  float n = sqrtf(fmaxf(n2, EPSV));
  float f1 = tanhf(0.5f * atanhf(fminf(n, CLIPV))) / n;

  float m2 = 0.f;
  #pragma unroll
  for (int j = 0; j < 3; j++) { v[j] *= f1; m2 += v[j] * v[j]; }
  m2 = block_sum(m2, red);
  float n1 = sqrtf(fmaxf(m2, EPSV));
  float f2 = tanhf(ssb[b] * atanhf(fminf(n1, CLIPV))) / n1;

  float s2 = 0.f;
  #pragma unroll
  for (int j = 0; j < 3; j++) { int e = t + j * 256; v[j] *= f2; s2 += v[j] * v[j]; Q[row * EE + e] = v[j]; }
  s2 = block_sum(s2, red);
  if (t == 0) o2[row] = s2;
}

// ---------- final: poincare_linear(out2,w_out,b_out) + mobius_add(x,.) + msm(sqrt(.5)) ----------
__global__ void k_final(const float* __restrict__ G, const float* __restrict__ xin,
                        const float* __restrict__ bout, const float* __restrict__ znout,
                        const float* __restrict__ x2, const float* __restrict__ o2,
                        float* __restrict__ outp) {
  __shared__ float red[256];
  long row = blockIdx.x;
  int t = threadIdx.x;
  float cx2 = o2[row];
  float dpl = fmaxf(1.0f - cx2, EPSV);

  float wv[2]; float sw2 = 0.f;
  #pragma unroll
  for (int j = 0; j < 2; j++) {
    int c = t + j * 256;
    float zn = znout[c];
    float u = G[row * CCH + c] / zn;
    float r2 = 2.0f * bout[c];
    float nm = 2.0f * u * coshf(r2) - (1.0f + cx2) * sinhf(r2);
    float y = 2.0f * zn * asinhf(nm / dpl);
    wv[j] = sinhf(y);
    sw2 += wv[j] * wv[j];
  }
  sw2 = block_sum(sw2, red);
  float pden = 1.0f + sqrtf(1.0f + sw2);

  float pv[2], xv[2];
  float xp = 0.f, p2 = 0.f;
  #pragma unroll
  for (int j = 0; j < 2; j++) {
    int c = t + j * 256;
    pv[j] = wv[j] / pden;
    xv[j] = xin[row * CCH + c];
    xp += xv[j] * pv[j]; p2 += pv[j] * pv[j];
  }
  xp = block_sum(xp, red);
  p2 = block_sum(p2, red);

  float xx = x2[row];
  float mden = fmaxf(1.0f + 2.0f * xp + xx * p2, EPSV);
  float cX = 1.0f + 2.0f * xp + p2;
  float cP = 1.0f - xx;
  float av[2]; float n2 = 0.f;
  #pragma unroll
  for (int j = 0; j < 2; j++) { av[j] = (cX * xv[j] + cP * pv[j]) / mden; n2 += av[j] * av[j]; }
  n2 = block_sum(n2, red);

  float n = sqrtf(fmaxf(n2, EPSV));
  float f = tanhf(0.70710678118654752f * atanhf(fminf(n, CLIPV))) / n;
  #pragma unroll
  for (int j = 0; j < 2; j++) { int c = t + j * 256; outp[row * CCH + c] = f * av[j]; }
}

extern "C" void kernel_launch(void* const* d_in, const int* in_sizes, int n_in,
                              void* d_out, int out_size, void* d_ws, size_t ws_size,
                              hipStream_t stream) {
  const float* x    = (const float*)d_in[0];
  const float* tgt  = (const float*)d_in[1];
  const float* enca = (const float*)d_in[2];
  const float* encb = (const float*)d_in[3];
  const void*  mraw = d_in[4];
  const float* win  = (const float*)d_in[5];
  const float* bin  = (const float*)d_in[6];
  const float* wout = (const float*)d_in[7];
  const float* bout = (const float*)d_in[8];
  const float* scalep = (const float*)d_in[9];

  float* out_main = (float*)d_out;
  float* out_attn = out_main + (long)BB * TT * CCH;   // [B,T,S] f32, scores->attn

  float* ws   = (float*)d_ws;
  float* Qw   = ws;                          // B*T*E (M1 -> q -> nom -> out2)
  float* enbs = Qw + (long)BB * TT * EE;     // B*S*E (gamma-scaled enc_b); reused as Gw
  float* Gw   = enbs;                        // B*T*CC (GEMM5 out, enbs dead by then)
  float* sm   = enbs + (long)BB * SS * EE;
  float* x2a  = sm; sm += BB * TT;
  float* q2a  = sm; sm += BB * TT;
  float* y2a  = sm; sm += BB * SS;
  float* gam  = sm; sm += BB * SS;
  float* denr = sm; sm += BB * TT;
  float* o2a  = sm; sm += BB * TT;
  float* znin = sm; sm += EE;
  float* znout= sm; sm += CCH;
  float* ssb  = sm; sm += BB;
  float* fmask= sm; sm += BB * SS;
  int*   mflag= (int*)sm; sm += 1;

  // mask canonicalization
  k_maskdet<<<1, 256, 0, stream>>>((const unsigned char*)mraw, mflag);
  k_maskconv<<<BB * SS / 256, 256, 0, stream>>>(mraw, mflag, fmask);

  // prep
  k_colnorm<<<3, 256, 0, stream>>>(win, znin, CCH, EE);
  k_colnorm<<<2, 256, 0, stream>>>(wout, znout, EE, CCH);
  k_row2<<<BB * TT, 256, 0, stream>>>(x, x2a, CCH);
  k_scaleB<<<BB * SS, 256, 0, stream>>>(encb, enbs, gam);
  k_y2a<<<BB * SS / 256, 256, 0, stream>>>(enca, y2a);
  k_sb<<<BB, 256, 0, stream>>>(fmask, ssb);

  // GEMM1: M1 = x @ w_in  -> Qw
  gemm_k<0><<<dim3(EE / 64, BB * TT / 64, 1), 256, 0, stream>>>(
      x, win, Qw, BB * TT, EE, CCH, 0, 0, 0, nullptr, nullptr, nullptr, nullptr);

  k_q<<<BB * TT, 256, 0, stream>>>(Qw, tgt, bin, znin, x2a, q2a);

  // GEMM2 (batched) + dist epilogue: scores -> out_attn
  gemm_k<1><<<dim3(SS / 64, TT / 64, BB), 256, 0, stream>>>(
      Qw, enca, out_attn, TT, SS, EE,
      (long)TT * EE, (long)EE * SS, (long)TT * SS, q2a, y2a, fmask, scalep);

  k_softmax<<<BB * TT, 256, 0, stream>>>(out_attn, gam, denr);

  // GEMM4 (batched): nom = attn @ (gamma*enc_b) -> Qw
  gemm_k<0><<<dim3(EE / 64, TT / 64, BB), 256, 0, stream>>>(
      out_attn, enbs, Qw, TT, EE, SS,
      (long)TT * SS, (long)SS * EE, (long)TT * EE, nullptr, nullptr, nullptr, nullptr);

  k_mid<<<BB * TT, 256, 0, stream>>>(Qw, denr, ssb, o2a);

  // GEMM5: M3 = out2 @ w_out -> Gw
  gemm_k<0><<<dim3(CCH / 64, BB * TT / 64, 1), 256, 0, stream>>>(
      Qw, wout, Gw, BB * TT, CCH, EE, 0, 0, 0, nullptr, nullptr, nullptr, nullptr);

  k_final<<<BB * TT, 256, 0, stream>>>(Gw, x, bout, znout, x2a, o2a, out_main);
}

// Round 4
// 1672.754 us; speedup vs baseline: 1.6083x; 1.6083x over previous
//
#include <hip/hip_runtime.h>
#include <hip/hip_bf16.h>
#include <math.h>

#define BB 16
#define TT 1024
#define SS 1024
#define CCH 512
#define EE 768
#define EPSV 1e-15f
#define CLIPV (1.0f - 1e-5f)

#define BM 128
#define BN 128
#define BK 32
#define LDT 40   // LDS row stride in shorts (80 B, 16B-aligned)

typedef __attribute__((ext_vector_type(8))) short short8_t;
typedef __attribute__((ext_vector_type(4))) short short4_t;
typedef __attribute__((ext_vector_type(4))) float floatx4;

union BFU { __hip_bfloat16 b; short s; };

static __device__ __forceinline__ void bsplit(float x, short& h, short& l) {
  BFU u1; u1.b = __float2bfloat16(x);
  float hf = __bfloat162float(u1.b);
  BFU u2; u2.b = __float2bfloat16(x - hf);
  h = u1.s; l = u2.s;
}

__device__ __forceinline__ float block_sum(float v, float* red) {
  int t = threadIdx.x;
  red[t] = v; __syncthreads();
  #pragma unroll
  for (int s = 128; s > 0; s >>= 1) { if (t < s) red[t] += red[t + s]; __syncthreads(); }
  float r = red[0]; __syncthreads();
  return r;
}

__device__ __forceinline__ float block_max(float v, float* red) {
  int t = threadIdx.x;
  red[t] = v; __syncthreads();
  #pragma unroll
  for (int s = 128; s > 0; s >>= 1) { if (t < s) red[t] = fmaxf(red[t], red[t + s]); __syncthreads(); }
  float r = red[0]; __syncthreads();
  return r;
}

// ---------- mask dtype detection + conversion ----------
__global__ void k_maskdet(const unsigned char* __restrict__ mb, int* __restrict__ flag) {
  __shared__ int any;
  if (threadIdx.x == 0) any = 0;
  __syncthreads();
  int local = 0;
  for (int i = threadIdx.x; i < BB * SS; i += 256)
    if ((i & 3) && mb[i]) local = 1;
  if (local) atomicOr(&any, 1);
  __syncthreads();
  if (threadIdx.x == 0) *flag = any;
}

__global__ void k_maskconv(const void* __restrict__ mraw, const int* __restrict__ flag,
                           float* __restrict__ fmask) {
  int i = blockIdx.x * 256 + threadIdx.x;
  if (i >= BB * SS) return;
  int f = *flag;
  int v = f ? (int)((const unsigned char*)mraw)[i] : ((const int*)mraw)[i];
  fmask[i] = v ? 1.0f : 0.0f;
}

// ---------- prep ----------
__global__ void k_colnorm(const float* __restrict__ z, float* __restrict__ zn, int K, int N) {
  int e = blockIdx.x * blockDim.x + threadIdx.x;
  if (e >= N) return;
  float s = 0.f;
  for (int k = 0; k < K; k++) { float v = z[(long)k * N + e]; s += v * v; }
  zn[e] = sqrtf(fmaxf(s, EPSV));
}

__global__ void k_row2(const float* __restrict__ xp, float* __restrict__ out, int D) {
  __shared__ float red[256];
  long row = blockIdx.x;
  float s = 0.f;
  for (int c = threadIdx.x; c < D; c += 256) { float v = xp[row * D + c]; s += v * v; }
  s = block_sum(s, red);
  if (threadIdx.x == 0) out[row] = s;
}

// gamma[b,s] = 2/max(1-|encb row|^2, EPS)
__global__ void k_gamma(const float* __restrict__ encb, float* __restrict__ gam) {
  __shared__ float red[256];
  long row = blockIdx.x;
  int t = threadIdx.x;
  float s2 = 0.f;
  #pragma unroll
  for (int j = 0; j < 3; j++) { float v = encb[row * EE + t + j * 256]; s2 += v * v; }
  s2 = block_sum(s2, red);
  if (t == 0) gam[row] = 2.0f / fmaxf(1.0f - s2, EPSV);
}

// y2a[b,s] = sum_e enc_a[b,e,s]^2  (enc_a is [B,E,S]); grid (S/64, B), 256 thr
__global__ void k_y2b(const float* __restrict__ enca, float* __restrict__ y2a) {
  __shared__ float red[256];
  int b = blockIdx.y, s0 = blockIdx.x * 64;
  int si = threadIdx.x & 63, eg = threadIdx.x >> 6;
  const float* p = enca + (long)b * EE * SS + s0 + si;
  float acc = 0.f;
  for (int e = eg; e < EE; e += 4) { float v = p[(long)e * SS]; acc += v * v; }
  red[threadIdx.x] = acc; __syncthreads();
  if (eg == 0)
    y2a[(long)b * SS + s0 + si] = red[si] + red[si + 64] + red[si + 128] + red[si + 192];
}

__global__ void k_sb(const float* __restrict__ fmask, float* __restrict__ ssb) {
  __shared__ float red[256];
  int b = blockIdx.x;
  float cnt = 0.f;
  for (int s = threadIdx.x; s < SS; s += 256) cnt += fmask[(long)b * SS + s];
  cnt = block_sum(cnt, red);
  if (threadIdx.x == 0) ssb[b] = sqrtf((float)SS - cnt);
}

// ---------- transpose + bf16 hi/lo split (optional per-input-row scale) ----------
// in: [R,C] fp32 (batch stride sin). out: [C,R] bf16 hi/lo (batch stride sout).
// rs: per-input-row scale (rs[z*R + r]) or nullptr. grid (C/32, R/32, B), block (32,8).
__global__ void k_tsp(const float* __restrict__ in, short* __restrict__ oh,
                      short* __restrict__ ol, const float* __restrict__ rs,
                      int R, int C, long sin, long sout) {
  __shared__ float tile[32][33];
  int z = blockIdx.z;
  const float* ib = in + (long)z * sin;
  short* ohb = oh + (long)z * sout;
  short* olb = ol + (long)z * sout;
  int c0 = blockIdx.x * 32, r0 = blockIdx.y * 32;
  int tx = threadIdx.x, ty = threadIdx.y;
  #pragma unroll
  for (int i = 0; i < 4; i++) {
    int rr = ty + i * 8;
    float v = ib[(long)(r0 + rr) * C + c0 + tx];
    if (rs) v *= rs[(long)z * R + r0 + rr];
    tile[rr][tx] = v;
  }
  __syncthreads();
  #pragma unroll
  for (int i = 0; i < 4; i++) {
    int cc = ty + i * 8;
    float v = tile[tx][cc];
    short h, l; bsplit(v, h, l);
    long o = (long)(c0 + cc) * R + r0 + tx;
    ohb[o] = h; olb[o] = l;
  }
}

// ---------- split-bf16 MFMA GEMM:  C = A(f32,[M,K]) @ B, with B given as
// BT hi/lo bf16 in [N,K] layout. EPI=1 fuses the Poincare distance+mask. ----------
template <int EPI>
__global__ __launch_bounds__(256)
void mgemm(const float* __restrict__ A, const short* __restrict__ BTh,
           const short* __restrict__ BTl, float* __restrict__ Cm,
           int M, int N, int K, long sA, long sBT, long sC,
           const float* __restrict__ q2, const float* __restrict__ y2a,
           const float* __restrict__ fmask, const float* __restrict__ scalep) {
  __shared__ short Ah[BM * LDT];
  __shared__ short Al[BM * LDT];
  __shared__ short Bh[BN * LDT];
  __shared__ short Bl[BN * LDT];

  int z = blockIdx.z;
  const float* Ab = A + (long)z * sA;
  const short* Bhb = BTh + (long)z * sBT;
  const short* Blb = BTl + (long)z * sBT;
  float* Cb = Cm + (long)z * sC;
  int m0 = blockIdx.y * BM, n0 = blockIdx.x * BN;
  int t = threadIdx.x;
  int w = t >> 6, l = t & 63;
  int wr = w >> 1, wc = w & 1;
  int quad = l >> 4, lm = l & 15;

  floatx4 acc[4][4];
  #pragma unroll
  for (int i = 0; i < 4; i++)
    #pragma unroll
    for (int j = 0; j < 4; j++) acc[i][j] = (floatx4){0.f, 0.f, 0.f, 0.f};

  for (int k0 = 0; k0 < K; k0 += BK) {
    // stage A (fp32 -> hi/lo bf16)
    #pragma unroll
    for (int u = 0; u < 4; u++) {
      int idx = t + u * 256;
      int row = idx >> 3, c4 = (idx & 7) * 4;
      floatx4 v = *(const floatx4*)&Ab[(long)(m0 + row) * K + k0 + c4];
      short4_t h4, l4;
      #pragma unroll
      for (int c = 0; c < 4; c++) { short hh, ll; bsplit(v[c], hh, ll); h4[c] = hh; l4[c] = ll; }
      *(short4_t*)&Ah[row * LDT + c4] = h4;
      *(short4_t*)&Al[row * LDT + c4] = l4;
    }
    // stage B (already bf16 hi/lo in [N,K])
    #pragma unroll
    for (int u = 0; u < 2; u++) {
      int idx = t + u * 256;
      int row = idx >> 2, c8 = (idx & 3) * 8;
      *(short8_t*)&Bh[row * LDT + c8] = *(const short8_t*)&Bhb[(long)(n0 + row) * K + k0 + c8];
      *(short8_t*)&Bl[row * LDT + c8] = *(const short8_t*)&Blb[(long)(n0 + row) * K + k0 + c8];
    }
    __syncthreads();

    short8_t bfh[4], bfl[4];
    #pragma unroll
    for (int nj = 0; nj < 4; nj++) {
      int n = wc * 64 + nj * 16 + lm;
      bfh[nj] = *(const short8_t*)&Bh[n * LDT + quad * 8];
      bfl[nj] = *(const short8_t*)&Bl[n * LDT + quad * 8];
    }
    #pragma unroll
    for (int mi = 0; mi < 4; mi++) {
      int m = wr * 64 + mi * 16 + lm;
      short8_t afh = *(const short8_t*)&Ah[m * LDT + quad * 8];
      short8_t afl = *(const short8_t*)&Al[m * LDT + quad * 8];
      #pragma unroll
      for (int nj = 0; nj < 4; nj++) {
        acc[mi][nj] = __builtin_amdgcn_mfma_f32_16x16x32_bf16(afh, bfh[nj], acc[mi][nj], 0, 0, 0);
        acc[mi][nj] = __builtin_amdgcn_mfma_f32_16x16x32_bf16(afh, bfl[nj], acc[mi][nj], 0, 0, 0);
        acc[mi][nj] = __builtin_amdgcn_mfma_f32_16x16x32_bf16(afl, bfh[nj], acc[mi][nj], 0, 0, 0);
      }
    }
    __syncthreads();
  }

  float inv_es = 1.0f;
  if constexpr (EPI == 1) inv_es = 1.0f / expf(scalep[0]);

  #pragma unroll
  for (int mi = 0; mi < 4; mi++) {
    #pragma unroll
    for (int r = 0; r < 4; r++) {
      int gm = m0 + wr * 64 + mi * 16 + quad * 4 + r;
      #pragma unroll
      for (int nj = 0; nj < 4; nj++) {
        int gn = n0 + wc * 64 + nj * 16 + lm;
        float c = acc[mi][nj][r];
        if constexpr (EPI == 0) {
          Cb[(long)gm * N + gn] = c;
        } else {
          float xv = q2[(long)z * M + gm];
          float yv = y2a[(long)z * N + gn];
          float num = fmaxf(xv - 2.0f * c + yv, 0.0f);
          float den = fmaxf(1.0f - 2.0f * c + xv * yv, EPSV);
          float mm = sqrtf(num / den);
          float sc = -2.0f * atanhf(fminf(mm, CLIPV)) * inv_es;
          if (fmask[(long)z * N + gn] > 0.5f) sc = -INFINITY;
          Cb[(long)gm * N + gn] = sc;
        }
      }
    }
  }
}

// ---------- q = msm(sqrt(.5), mobius_add(tgt, poincare_linear(x,w_in,b_in))) ----------
__global__ void k_q(float* __restrict__ Q, const float* __restrict__ tgt,
                    const float* __restrict__ bin, const float* __restrict__ znin,
                    const float* __restrict__ x2, float* __restrict__ q2) {
  __shared__ float red[256];
  long row = blockIdx.x;
  int t = threadIdx.x;
  float cx2 = x2[row];
  float dpl = fmaxf(1.0f - cx2, EPSV);

  float wv[3]; float sw2 = 0.f;
  #pragma unroll
  for (int j = 0; j < 3; j++) {
    int e = t + j * 256;
    float zn = znin[e];
    float u = Q[row * EE + e] / zn;
    float r2 = 2.0f * bin[e];
    float nm = 2.0f * u * coshf(r2) - (1.0f + cx2) * sinhf(r2);
    float y = 2.0f * zn * asinhf(nm / dpl);
    wv[j] = sinhf(y);
    sw2 += wv[j] * wv[j];
  }
  sw2 = block_sum(sw2, red);
  float pden = 1.0f + sqrtf(1.0f + sw2);

  float pv[3], tv[3];
  float tp = 0.f, p2 = 0.f, t2 = 0.f;
  #pragma unroll
  for (int j = 0; j < 3; j++) {
    int e = t + j * 256;
    pv[j] = wv[j] / pden;
    tv[j] = tgt[row * EE + e];
    tp += tv[j] * pv[j]; p2 += pv[j] * pv[j]; t2 += tv[j] * tv[j];
  }
  tp = block_sum(tp, red);
  p2 = block_sum(p2, red);
  t2 = block_sum(t2, red);

  float mden = fmaxf(1.0f + 2.0f * tp + t2 * p2, EPSV);
  float cT = 1.0f + 2.0f * tp + p2;
  float cP = 1.0f - t2;
  float av[3]; float n2 = 0.f;
  #pragma unroll
  for (int j = 0; j < 3; j++) { av[j] = (cT * tv[j] + cP * pv[j]) / mden; n2 += av[j] * av[j]; }
  n2 = block_sum(n2, red);

  float n = sqrtf(fmaxf(n2, EPSV));
  float f = tanhf(0.70710678118654752f * atanhf(fminf(n, CLIPV))) / n;
  #pragma unroll
  for (int j = 0; j < 3; j++) { int e = t + j * 256; Q[row * EE + e] = f * av[j]; }
  if (t == 0) q2[row] = f * f * n2;
}

// ---------- softmax in-place; den = sum attn*(gamma-1) ----------
__global__ void k_softmax(float* __restrict__ A, const float* __restrict__ gam,
                          float* __restrict__ denr) {
  __shared__ float red[256];
  long row = blockIdx.x;
  int b = (int)(row / TT);
  int t = threadIdx.x;
  float* rowp = A + row * SS;

  float v[4];
  float mx = -INFINITY;
  #pragma unroll
  for (int j = 0; j < 4; j++) { v[j] = rowp[t + j * 256]; mx = fmaxf(mx, v[j]); }
  mx = block_max(mx, red);
  bool dead = !(mx > -INFINITY) || (mx != mx);
  float sum = 0.f;
  #pragma unroll
  for (int j = 0; j < 4; j++) { v[j] = dead ? 0.f : expf(v[j] - mx); sum += v[j]; }
  sum = block_sum(sum, red);
  float inv = (sum > 0.f) ? 1.0f / sum : 0.f;
  float ds = 0.f;
  #pragma unroll
  for (int j = 0; j < 4; j++) {
    int s = t + j * 256;
    float a = v[j] * inv;
    rowp[s] = a;
    ds += a * (gam[(long)b * SS + s] - 1.0f);
  }
  ds = block_sum(ds, red);
  if (t == 0) denr[row] = (inv == 0.f) ? 1.0f : ds;
}

// ---------- out2 = msm(sqrt(s_b), msm(0.5, nom/den)) ----------
__global__ void k_mid(float* __restrict__ Q, const float* __restrict__ denr,
                      const float* __restrict__ ssb, float* __restrict__ o2) {
  __shared__ float red[256];
  long row = blockIdx.x;
  int b = (int)(row / TT);
  int t = threadIdx.x;
  float d = denr[row];
  if (fabsf(d) < 1e-10f) d = 1e-10f;

  float v[3]; float n2 = 0.f;
  #pragma unroll
  for (int j = 0; j < 3; j++) { int e = t + j * 256; v[j] = Q[row * EE + e] / d; n2 += v[j] * v[j]; }
  n2 = block_sum(n2, red);
  float n = sqrtf(fmaxf(n2, EPSV));
  float f1 = tanhf(0.5f * atanhf(fminf(n, CLIPV))) / n;

  float m2 = 0.f;
  #pragma unroll
  for (int j = 0; j < 3; j++) { v[j] *= f1; m2 += v[j] * v[j]; }
  m2 = block_sum(m2, red);
  float n1 = sqrtf(fmaxf(m2, EPSV));
  float f2 = tanhf(ssb[b] * atanhf(fminf(n1, CLIPV))) / n1;

  float s2 = 0.f;
  #pragma unroll
  for (int j = 0; j < 3; j++) { int e = t + j * 256; v[j] *= f2; s2 += v[j] * v[j]; Q[row * EE + e] = v[j]; }
  s2 = block_sum(s2, red);
  if (t == 0) o2[row] = s2;
}

// ---------- final epilogue ----------
__global__ void k_final(const float* __restrict__ G, const float* __restrict__ xin,
                        const float* __restrict__ bout, const float* __restrict__ znout,
                        const float* __restrict__ x2, const float* __restrict__ o2,
                        float* __restrict__ outp) {
  __shared__ float red[256];
  long row = blockIdx.x;
  int t = threadIdx.x;
  float cx2 = o2[row];
  float dpl = fmaxf(1.0f - cx2, EPSV);

  float wv[2]; float sw2 = 0.f;
  #pragma unroll
  for (int j = 0; j < 2; j++) {
    int c = t + j * 256;
    float zn = znout[c];
    float u = G[row * CCH + c] / zn;
    float r2 = 2.0f * bout[c];
    float nm = 2.0f * u * coshf(r2) - (1.0f + cx2) * sinhf(r2);
    float y = 2.0f * zn * asinhf(nm / dpl);
    wv[j] = sinhf(y);
    sw2 += wv[j] * wv[j];
  }
  sw2 = block_sum(sw2, red);
  float pden = 1.0f + sqrtf(1.0f + sw2);

  float pv[2], xv[2];
  float xp = 0.f, p2 = 0.f;
  #pragma unroll
  for (int j = 0; j < 2; j++) {
    int c = t + j * 256;
    pv[j] = wv[j] / pden;
    xv[j] = xin[row * CCH + c];
    xp += xv[j] * pv[j]; p2 += pv[j] * pv[j];
  }
  xp = block_sum(xp, red);
  p2 = block_sum(p2, red);

  float xx = x2[row];
  float mden = fmaxf(1.0f + 2.0f * xp + xx * p2, EPSV);
  float cX = 1.0f + 2.0f * xp + p2;
  float cP = 1.0f - xx;
  float av[2]; float n2 = 0.f;
  #pragma unroll
  for (int j = 0; j < 2; j++) { av[j] = (cX * xv[j] + cP * pv[j]) / mden; n2 += av[j] * av[j]; }
  n2 = block_sum(n2, red);

  float n = sqrtf(fmaxf(n2, EPSV));
  float f = tanhf(0.70710678118654752f * atanhf(fminf(n, CLIPV))) / n;
  #pragma unroll
  for (int j = 0; j < 2; j++) { int c = t + j * 256; outp[row * CCH + c] = f * av[j]; }
}

extern "C" void kernel_launch(void* const* d_in, const int* in_sizes, int n_in,
                              void* d_out, int out_size, void* d_ws, size_t ws_size,
                              hipStream_t stream) {
  const float* x    = (const float*)d_in[0];
  const float* tgt  = (const float*)d_in[1];
  const float* enca = (const float*)d_in[2];
  const float* encb = (const float*)d_in[3];
  const void*  mraw = d_in[4];
  const float* win  = (const float*)d_in[5];
  const float* bin  = (const float*)d_in[6];
  const float* wout = (const float*)d_in[7];
  const float* bout = (const float*)d_in[8];
  const float* scalep = (const float*)d_in[9];

  float* out_main = (float*)d_out;
  float* out_attn = out_main + (long)BB * TT * CCH;   // [B,T,S] f32 scores->attn

  char* wb = (char*)d_ws;
  const long QW_B   = (long)BB * TT * EE * 4;          // 50.3 MB
  const long TSP_H  = (long)BB * SS * EE * 2;          // 25.2 MB (one bf16 plane)
  float* Qw      = (float*)wb;                  wb += QW_B;
  short* tspH    = (short*)wb;                  wb += TSP_H;
  short* tspL    = (short*)wb;                  wb += TSP_H;
  float* Gw      = (float*)tspH;                // GEMM5 out (33.5MB), after ebT dead
  short* winTh   = (short*)wb;                  wb += (long)CCH * EE * 2;
  short* winTl   = (short*)wb;                  wb += (long)CCH * EE * 2;
  short* woutTh  = (short*)wb;                  wb += (long)EE * CCH * 2;
  short* woutTl  = (short*)wb;                  wb += (long)EE * CCH * 2;
  float* sm      = (float*)wb;
  float* x2a  = sm; sm += BB * TT;
  float* q2a  = sm; sm += BB * TT;
  float* y2a  = sm; sm += BB * SS;
  float* gam  = sm; sm += BB * SS;
  float* denr = sm; sm += BB * TT;
  float* o2a  = sm; sm += BB * TT;
  float* znin = sm; sm += EE;
  float* znout= sm; sm += CCH;
  float* ssb  = sm; sm += BB;
  float* fmask= sm; sm += BB * SS;
  int*   mflag= (int*)sm; sm += 1;

  // mask canonicalization
  k_maskdet<<<1, 256, 0, stream>>>((const unsigned char*)mraw, mflag);
  k_maskconv<<<BB * SS / 256, 256, 0, stream>>>(mraw, mflag, fmask);

  // prep
  k_colnorm<<<3, 256, 0, stream>>>(win, znin, CCH, EE);
  k_colnorm<<<2, 256, 0, stream>>>(wout, znout, EE, CCH);
  k_row2<<<BB * TT, 256, 0, stream>>>(x, x2a, CCH);
  k_gamma<<<BB * SS, 256, 0, stream>>>(encb, gam);
  k_y2b<<<dim3(SS / 64, BB), 256, 0, stream>>>(enca, y2a);
  k_sb<<<BB, 256, 0, stream>>>(fmask, ssb);

  // weight transposes + split
  k_tsp<<<dim3(EE / 32, CCH / 32, 1), dim3(32, 8), 0, stream>>>(
      win, winTh, winTl, nullptr, CCH, EE, 0, 0);
  k_tsp<<<dim3(CCH / 32, EE / 32, 1), dim3(32, 8), 0, stream>>>(
      wout, woutTh, woutTl, nullptr, EE, CCH, 0, 0);

  // enc_a [E,S] -> eaT [S,E] hi/lo  (into tsp buffers)
  k_tsp<<<dim3(SS / 32, EE / 32, BB), dim3(32, 8), 0, stream>>>(
      enca, tspH, tspL, nullptr, EE, SS, (long)EE * SS, (long)SS * EE);

  // GEMM1: M1 = x @ w_in -> Qw
  mgemm<0><<<dim3(EE / BN, BB * TT / BM, 1), 256, 0, stream>>>(
      x, winTh, winTl, Qw, BB * TT, EE, CCH, 0, 0, 0,
      nullptr, nullptr, nullptr, nullptr);

  k_q<<<BB * TT, 256, 0, stream>>>(Qw, tgt, bin, znin, x2a, q2a);

  // GEMM2 (batched) + dist epilogue: scores -> out_attn
  mgemm<1><<<dim3(SS / BN, TT / BM, BB), 256, 0, stream>>>(
      Qw, tspH, tspL, out_attn, TT, SS, EE,
      (long)TT * EE, (long)SS * EE, (long)TT * SS, q2a, y2a, fmask, scalep);

  // enc_b [S,E] scaled by gamma -> ebT [E,S] hi/lo (overwrites eaT)
  k_tsp<<<dim3(EE / 32, SS / 32, BB), dim3(32, 8), 0, stream>>>(
      encb, tspH, tspL, gam, SS, EE, (long)SS * EE, (long)EE * SS);

  k_softmax<<<BB * TT, 256, 0, stream>>>(out_attn, gam, denr);

  // GEMM4 (batched): nom = attn @ (gamma*enc_b) -> Qw
  mgemm<0><<<dim3(EE / BN, TT / BM, BB), 256, 0, stream>>>(
      out_attn, tspH, tspL, Qw, TT, EE, SS,
      (long)TT * SS, (long)EE * SS, (long)TT * EE, nullptr, nullptr, nullptr, nullptr);

  k_mid<<<BB * TT, 256, 0, stream>>>(Qw, denr, ssb, o2a);

  // GEMM5: M3 = out2 @ w_out -> Gw (aliases tsp buffers; ebT dead)
  mgemm<0><<<dim3(CCH / BN, BB * TT / BM, 1), 256, 0, stream>>>(
      Qw, woutTh, woutTl, Gw, BB * TT, CCH, EE, 0, 0, 0,
      nullptr, nullptr, nullptr, nullptr);

  k_final<<<BB * TT, 256, 0, stream>>>(Gw, x, bout, znout, x2a, o2a, out_main);
}